// Round 5
// baseline (220.983 us; speedup 1.0000x reference)
//
#include <hip/hip_runtime.h>
#include <hip/hip_cooperative_groups.h>

namespace cg = cooperative_groups;

// Problem constants (GraphConvolution_71923522339430)
#define D_IN  128
#define D_OUT 64

// Native clang vector types (HIP float4 class is rejected by
// __builtin_nontemporal_* and can't hold _Float16).
typedef float    nfloat4 __attribute__((ext_vector_type(4)));
typedef _Float16 half4_t __attribute__((ext_vector_type(4)));   // 8 B

// ---------------------------------------------------------------------------
// Single cooperative kernel, three phases:
//   Phase A (grid-stride over units): units [0, gemm_units) = 64-node gemm
//     tiles h = x @ W (fp16 out); units [gemm_units, total) = 1024-edge
//     row_ptr chunks from sorted edge_dst. Data-independent, interleaved.
//   grid.sync()  -- device-scope barrier + memory visibility for h/row_ptr.
//   Phase B (grid-stride, one wave per node): out = bias + sum vals*h[src].
//
// Round-7 changes vs round-6:
//   * Removed the second kernel launch (~4 us gap) via cooperative launch.
//   * Gemm no longer stages X in LDS: with the 4x4 thread tile the 16
//     tx-threads of a row group read IDENTICAL x addresses, so a direct
//     global load broadcasts intra-instruction; each x byte is read exactly
//     once (4x16B=64B per instr). LDS = W only (32 KB, staged once per
//     block, no restaging, one __syncthreads total in phase A).
//     -> 4 blocks/CU (16 waves/CU) for both phases.
//   * Ws read pattern unchanged (2-way b128 conflict = free per m136).
//   * Aggregate body unchanged (proven); bias load amortized over ~12
//     nodes per wave.
// ---------------------------------------------------------------------------
__global__ __launch_bounds__(256, 4) void fused_gcn_kernel(
    const float* __restrict__ x, const float* __restrict__ w,
    _Float16* __restrict__ h, int n_nodes,
    const int* __restrict__ dst, int* __restrict__ row_ptr, int n_edges,
    const int* __restrict__ src, const float* __restrict__ vals,
    const float* __restrict__ bias, float* __restrict__ out,
    int gemm_units, int total_units)
{
    __shared__ float Ws[128 * 64];   // 32768 B, full W

    const int t = threadIdx.x;

    // Stage full W once per block: 2048 float4, 8 per thread.
    #pragma unroll
    for (int j = 0; j < 8; ++j) {
        int idx = j * 256 + t;
        int k   = idx >> 4;
        int c   = idx & 15;
        *(float4*)&Ws[k * 64 + c * 4] = *(const float4*)&w[k * D_OUT + c * 4];
    }
    __syncthreads();

    const int tx = t & 15;           // dim group
    const int ty = t >> 4;           // node group
    const int d0 = tx * 4;
    const int n0 = ty * 4;

    // ---- Phase A ----
    for (int u = blockIdx.x; u < total_units; u += gridDim.x) {
        if (u < gemm_units) {
            const int node0 = u * 64;
            const int r0    = node0 + n0;
            // Clamped row indices: loads always in-bounds, stores guarded.
            int ri[4];
            #pragma unroll
            for (int i = 0; i < 4; ++i) {
                int g = r0 + i;
                ri[i] = (g < n_nodes) ? g : (n_nodes - 1);
            }

            float4 acc[4];
            #pragma unroll
            for (int i = 0; i < 4; ++i) acc[i] = make_float4(0.f, 0.f, 0.f, 0.f);

            #pragma unroll 2
            for (int k = 0; k < D_IN; k += 4) {
                float4 xa[4], wb[4];
                #pragma unroll
                for (int i = 0; i < 4; ++i)
                    xa[i] = *(const float4*)&x[(size_t)ri[i] * D_IN + k];
                #pragma unroll
                for (int r = 0; r < 4; ++r)
                    wb[r] = *(const float4*)&Ws[(k + r) * 64 + d0];
                #pragma unroll
                for (int i = 0; i < 4; ++i) {
                    acc[i].x = fmaf(xa[i].x, wb[0].x, acc[i].x);
                    acc[i].y = fmaf(xa[i].x, wb[0].y, acc[i].y);
                    acc[i].z = fmaf(xa[i].x, wb[0].z, acc[i].z);
                    acc[i].w = fmaf(xa[i].x, wb[0].w, acc[i].w);
                    acc[i].x = fmaf(xa[i].y, wb[1].x, acc[i].x);
                    acc[i].y = fmaf(xa[i].y, wb[1].y, acc[i].y);
                    acc[i].z = fmaf(xa[i].y, wb[1].z, acc[i].z);
                    acc[i].w = fmaf(xa[i].y, wb[1].w, acc[i].w);
                    acc[i].x = fmaf(xa[i].z, wb[2].x, acc[i].x);
                    acc[i].y = fmaf(xa[i].z, wb[2].y, acc[i].y);
                    acc[i].z = fmaf(xa[i].z, wb[2].z, acc[i].z);
                    acc[i].w = fmaf(xa[i].z, wb[2].w, acc[i].w);
                    acc[i].x = fmaf(xa[i].w, wb[3].x, acc[i].x);
                    acc[i].y = fmaf(xa[i].w, wb[3].y, acc[i].y);
                    acc[i].z = fmaf(xa[i].w, wb[3].z, acc[i].z);
                    acc[i].w = fmaf(xa[i].w, wb[3].w, acc[i].w);
                }
            }

            #pragma unroll
            for (int i = 0; i < 4; ++i) {
                int gn = r0 + i;
                if (gn < n_nodes) {
                    half4_t hv;
                    hv.x = (_Float16)acc[i].x;
                    hv.y = (_Float16)acc[i].y;
                    hv.z = (_Float16)acc[i].z;
                    hv.w = (_Float16)acc[i].w;
                    *(half4_t*)&h[(size_t)gn * D_OUT + d0] = hv;
                }
            }
        } else {
            // ---- row_ptr build: 1024 edges per unit, stride-256 x4 ----
            int rb   = u - gemm_units;
            int base = rb * 1024 + t;
            #pragma unroll
            for (int j = 0; j < 4; ++j) {
                int e = base + j * 256;
                if (e < n_edges) {
                    int d1 = dst[e];
                    int dp = (e == 0) ? -1 : dst[e - 1];
                    for (int q = dp + 1; q <= d1; ++q) row_ptr[q] = e;
                    if (e == n_edges - 1) {
                        for (int q = d1 + 1; q <= n_nodes; ++q) row_ptr[q] = n_edges;
                    }
                }
            }
        }
    }

    // All h rows + row_ptr visible to every block after this.
    cg::this_grid().sync();

    // ---- Phase B: aggregate ----
    const int lane = t & 63;
    const int sub  = lane >> 4;      // edge slot 0..3
    const int d4   = lane & 15;      // half4 chunk of the 64-dim row
    const int wv   = (int)((blockIdx.x * blockDim.x + t) >> 6);
    const int nwv  = (int)((gridDim.x * blockDim.x) >> 6);
    const half4_t* __restrict__ h4 = (const half4_t*)h;

    // Loaded once per wave, reused across all its nodes.
    float4 bb = *(const float4*)&bias[d4 * 4];

    for (int node = wv; node < n_nodes; node += nwv) {
        int b = row_ptr[node];
        int e = row_ptr[node + 1];

        float4 acc0 = make_float4(0.f, 0.f, 0.f, 0.f);
        float4 acc1 = make_float4(0.f, 0.f, 0.f, 0.f);

        int k = b + sub;
        // 16 edges per iteration: 4 gathers in flight per wave.
        for (; k + 12 < e; k += 16) {
            int   s0 = __builtin_nontemporal_load(&src[k]);
            int   s1 = __builtin_nontemporal_load(&src[k + 4]);
            int   s2 = __builtin_nontemporal_load(&src[k + 8]);
            int   s3 = __builtin_nontemporal_load(&src[k + 12]);
            float v0 = __builtin_nontemporal_load(&vals[k]);
            float v1 = __builtin_nontemporal_load(&vals[k + 4]);
            float v2 = __builtin_nontemporal_load(&vals[k + 8]);
            float v3 = __builtin_nontemporal_load(&vals[k + 12]);
            half4_t h0 = h4[(size_t)s0 * 16 + d4];
            half4_t h1 = h4[(size_t)s1 * 16 + d4];
            half4_t h2 = h4[(size_t)s2 * 16 + d4];
            half4_t h3 = h4[(size_t)s3 * 16 + d4];
            acc0.x = fmaf(v0, (float)h0.x, acc0.x);
            acc0.y = fmaf(v0, (float)h0.y, acc0.y);
            acc0.z = fmaf(v0, (float)h0.z, acc0.z);
            acc0.w = fmaf(v0, (float)h0.w, acc0.w);
            acc1.x = fmaf(v1, (float)h1.x, acc1.x);
            acc1.y = fmaf(v1, (float)h1.y, acc1.y);
            acc1.z = fmaf(v1, (float)h1.z, acc1.z);
            acc1.w = fmaf(v1, (float)h1.w, acc1.w);
            acc0.x = fmaf(v2, (float)h2.x, acc0.x);
            acc0.y = fmaf(v2, (float)h2.y, acc0.y);
            acc0.z = fmaf(v2, (float)h2.z, acc0.z);
            acc0.w = fmaf(v2, (float)h2.w, acc0.w);
            acc1.x = fmaf(v3, (float)h3.x, acc1.x);
            acc1.y = fmaf(v3, (float)h3.y, acc1.y);
            acc1.z = fmaf(v3, (float)h3.z, acc1.z);
            acc1.w = fmaf(v3, (float)h3.w, acc1.w);
        }
        // 8-edge remainder.
        for (; k + 4 < e; k += 8) {
            int   s0 = __builtin_nontemporal_load(&src[k]);
            int   s1 = __builtin_nontemporal_load(&src[k + 4]);
            float v0 = __builtin_nontemporal_load(&vals[k]);
            float v1 = __builtin_nontemporal_load(&vals[k + 4]);
            half4_t h0 = h4[(size_t)s0 * 16 + d4];
            half4_t h1 = h4[(size_t)s1 * 16 + d4];
            acc0.x = fmaf(v0, (float)h0.x, acc0.x);
            acc0.y = fmaf(v0, (float)h0.y, acc0.y);
            acc0.z = fmaf(v0, (float)h0.z, acc0.z);
            acc0.w = fmaf(v0, (float)h0.w, acc0.w);
            acc1.x = fmaf(v1, (float)h1.x, acc1.x);
            acc1.y = fmaf(v1, (float)h1.y, acc1.y);
            acc1.z = fmaf(v1, (float)h1.z, acc1.z);
            acc1.w = fmaf(v1, (float)h1.w, acc1.w);
        }
        // 1-edge remainder.
        if (k < e) {
            int   s0 = src[k];
            float v0 = vals[k];
            half4_t h0 = h4[(size_t)s0 * 16 + d4];
            acc0.x = fmaf(v0, (float)h0.x, acc0.x);
            acc0.y = fmaf(v0, (float)h0.y, acc0.y);
            acc0.z = fmaf(v0, (float)h0.z, acc0.z);
            acc0.w = fmaf(v0, (float)h0.w, acc0.w);
        }

        float4 acc;
        acc.x = acc0.x + acc1.x;
        acc.y = acc0.y + acc1.y;
        acc.z = acc0.z + acc1.z;
        acc.w = acc0.w + acc1.w;

        // Sum across the 4 edge slots (lanes differing in bits 4,5).
        #pragma unroll
        for (int off = 16; off < 64; off <<= 1) {
            acc.x += __shfl_xor(acc.x, off, 64);
            acc.y += __shfl_xor(acc.y, off, 64);
            acc.z += __shfl_xor(acc.z, off, 64);
            acc.w += __shfl_xor(acc.w, off, 64);
        }

        if (sub == 0) {
            nfloat4 o;
            o.x = acc.x + bb.x;
            o.y = acc.y + bb.y;
            o.z = acc.z + bb.z;
            o.w = acc.w + bb.w;
            __builtin_nontemporal_store(o, (nfloat4*)&out[(size_t)node * D_OUT + d4 * 4]);
        }
    }
}

// ---------------------------------------------------------------------------
extern "C" void kernel_launch(void* const* d_in, const int* in_sizes, int n_in,
                              void* d_out, int out_size, void* d_ws, size_t ws_size,
                              hipStream_t stream)
{
    const float* x         = (const float*)d_in[0];
    const int*   edge_src  = (const int*)  d_in[1];
    const int*   edge_dst  = (const int*)  d_in[2];
    const float* edge_vals = (const float*)d_in[3];
    const float* weight    = (const float*)d_in[4];
    const float* bias      = (const float*)d_in[5];
    float*       out       = (float*)d_out;

    const int n_nodes = in_sizes[0] / D_IN;   // 50000
    const int n_edges = in_sizes[1];          // 800000

    // Workspace layout: h [n_nodes*64 fp16] | row_ptr [(n_nodes+1) i32]
    _Float16* h       = (_Float16*)d_ws;
    int*      row_ptr = (int*)((char*)d_ws + (size_t)n_nodes * D_OUT * sizeof(_Float16));

    // Co-residency-safe grid size for the cooperative launch (cached; host
    // queries only — no stream ops, graph-capture safe).
    static int grid_blocks = 0;
    if (grid_blocks == 0) {
        int dev = 0;
        (void)hipGetDevice(&dev);
        int ncu = 256;
        (void)hipDeviceGetAttribute(&ncu, hipDeviceAttributeMultiprocessorCount, dev);
        int maxb = 0;
        if (hipOccupancyMaxActiveBlocksPerMultiprocessor(&maxb, fused_gcn_kernel, 256, 0)
                != hipSuccess || maxb < 1)
            maxb = 2;   // conservative: 32 KB LDS / <=128 VGPR always fits 2/CU
        grid_blocks = ncu * maxb;
        if (grid_blocks < 64) grid_blocks = 64;
    }

    int gemm_units  = (n_nodes + 63) / 64;       // 782
    int rp_units    = (n_edges + 1023) / 1024;   // 782
    int total_units = gemm_units + rp_units;

    void* args[] = {
        (void*)&x, (void*)&weight, (void*)&h, (void*)&n_nodes,
        (void*)&edge_dst, (void*)&row_ptr, (void*)&n_edges,
        (void*)&edge_src, (void*)&edge_vals,
        (void*)&bias, (void*)&out,
        (void*)&gemm_units, (void*)&total_units
    };
    hipLaunchCooperativeKernel((const void*)fused_gcn_kernel,
                               dim3(grid_blocks), dim3(256), args, 0, stream);
}

// Round 6
// 122.837 us; speedup vs baseline: 1.7990x; 1.7990x over previous
//
#include <hip/hip_runtime.h>

// Problem constants (GraphConvolution_71923522339430)
#define D_IN  128
#define D_OUT 64

// Native clang vector types (HIP float4 class is rejected by
// __builtin_nontemporal_* and can't hold _Float16).
typedef float    nfloat4 __attribute__((ext_vector_type(4)));
typedef _Float16 half4_t __attribute__((ext_vector_type(4)));   // 8 B

// ---------------------------------------------------------------------------
// Kernel 1 (fused): blocks [0, gemm_blocks) compute h = x @ W (h stored FP16);
// blocks [gemm_blocks, ...) build CSR row_ptr from sorted edge_dst.
//
// Round-8: REVERT to the round-6 structure (measured 123.65 us, best).
// The round-7 cooperative single-kernel experiment regressed to 220 us:
// dropping the X LDS staging made x loads 4-way divergent (64 B/instr),
// VGPR fell to 60 (no MLP), and grid.sync() serialized on stragglers ->
// VALUBusy 9.7%, 163 us in-kernel. Coalesced LDS staging + 2 launches wins.
//
// W staged in TWO 64-row halves (16 KB each): LDS 49 KB -> 3 blocks/CU.
// h stored fp16: halves aggregate gather traffic + L2 footprint.
// ---------------------------------------------------------------------------
__global__ __launch_bounds__(256, 3) void gemm_rowptr_kernel(
    const float* __restrict__ x, const float* __restrict__ w,
    _Float16* __restrict__ h, int n_nodes,
    const int* __restrict__ dst, int* __restrict__ row_ptr, int n_edges,
    int gemm_blocks)
{
    __shared__ float Xs[64 * 132];   // 33792 B
    __shared__ float Ws[64 * 64];    // 16384 B (one K-half of W)

    if ((int)blockIdx.x >= gemm_blocks) {
        // ---- row_ptr build: 1024 edges per block, stride-256 x4 ----
        int rb   = (int)blockIdx.x - gemm_blocks;
        int base = rb * 1024 + (int)threadIdx.x;
        #pragma unroll
        for (int j = 0; j < 4; ++j) {
            int e = base + j * 256;
            if (e < n_edges) {
                int d1 = dst[e];
                int d0 = (e == 0) ? -1 : dst[e - 1];
                for (int q = d0 + 1; q <= d1; ++q) row_ptr[q] = e;
                if (e == n_edges - 1) {
                    for (int q = d1 + 1; q <= n_nodes; ++q) row_ptr[q] = n_edges;
                }
            }
        }
        return;
    }

    const int t   = threadIdx.x;
    const int tx  = t & 15;          // dim group
    const int ty  = t >> 4;          // node group
    const int node0 = blockIdx.x * 64;

    const int d0 = tx * 4;
    const int n0 = ty * 4;

    // Stage X tile: 64 rows x 128 floats (full K range, staged once).
    #pragma unroll
    for (int j = 0; j < 8; ++j) {
        int idx = j * 256 + t;
        int r   = idx >> 5;
        int c   = idx & 31;
        int gn  = node0 + r;
        float4 v = make_float4(0.f, 0.f, 0.f, 0.f);
        if (gn < n_nodes) v = *(const float4*)&x[(size_t)gn * D_IN + c * 4];
        *(float4*)&Xs[r * 132 + c * 4] = v;
    }
    // Stage W half 0 (k = 0..63): 1024 float4, 4 per thread.
    #pragma unroll
    for (int j = 0; j < 4; ++j) {
        int idx = j * 256 + t;
        int kk  = idx >> 4;
        int c   = idx & 15;
        *(float4*)&Ws[kk * 64 + c * 4] = *(const float4*)&w[kk * D_OUT + c * 4];
    }
    __syncthreads();

    float4 acc[4];
    #pragma unroll
    for (int i = 0; i < 4; ++i) acc[i] = make_float4(0.f, 0.f, 0.f, 0.f);

    // ---- pass 0: k = 0..63 ----
    #pragma unroll 2
    for (int k = 0; k < 64; k += 4) {
        float4 xa[4], wb[4];
        #pragma unroll
        for (int i = 0; i < 4; ++i)
            xa[i] = *(const float4*)&Xs[(n0 + i) * 132 + k];
        #pragma unroll
        for (int r = 0; r < 4; ++r)
            wb[r] = *(const float4*)&Ws[(k + r) * 64 + d0];
        #pragma unroll
        for (int i = 0; i < 4; ++i) {
            acc[i].x = fmaf(xa[i].x, wb[0].x, acc[i].x);
            acc[i].y = fmaf(xa[i].x, wb[0].y, acc[i].y);
            acc[i].z = fmaf(xa[i].x, wb[0].z, acc[i].z);
            acc[i].w = fmaf(xa[i].x, wb[0].w, acc[i].w);
            acc[i].x = fmaf(xa[i].y, wb[1].x, acc[i].x);
            acc[i].y = fmaf(xa[i].y, wb[1].y, acc[i].y);
            acc[i].z = fmaf(xa[i].y, wb[1].z, acc[i].z);
            acc[i].w = fmaf(xa[i].y, wb[1].w, acc[i].w);
            acc[i].x = fmaf(xa[i].z, wb[2].x, acc[i].x);
            acc[i].y = fmaf(xa[i].z, wb[2].y, acc[i].y);
            acc[i].z = fmaf(xa[i].z, wb[2].z, acc[i].z);
            acc[i].w = fmaf(xa[i].z, wb[2].w, acc[i].w);
            acc[i].x = fmaf(xa[i].w, wb[3].x, acc[i].x);
            acc[i].y = fmaf(xa[i].w, wb[3].y, acc[i].y);
            acc[i].z = fmaf(xa[i].w, wb[3].z, acc[i].z);
            acc[i].w = fmaf(xa[i].w, wb[3].w, acc[i].w);
        }
    }

    // Swap in W half 1 (k = 64..127).
    __syncthreads();
    #pragma unroll
    for (int j = 0; j < 4; ++j) {
        int idx = j * 256 + t;
        int kk  = idx >> 4;
        int c   = idx & 15;
        *(float4*)&Ws[kk * 64 + c * 4] = *(const float4*)&w[(64 + kk) * D_OUT + c * 4];
    }
    __syncthreads();

    // ---- pass 1: k = 64..127 ----
    #pragma unroll 2
    for (int k = 0; k < 64; k += 4) {
        float4 xa[4], wb[4];
        #pragma unroll
        for (int i = 0; i < 4; ++i)
            xa[i] = *(const float4*)&Xs[(n0 + i) * 132 + 64 + k];
        #pragma unroll
        for (int r = 0; r < 4; ++r)
            wb[r] = *(const float4*)&Ws[(k + r) * 64 + d0];
        #pragma unroll
        for (int i = 0; i < 4; ++i) {
            acc[i].x = fmaf(xa[i].x, wb[0].x, acc[i].x);
            acc[i].y = fmaf(xa[i].x, wb[0].y, acc[i].y);
            acc[i].z = fmaf(xa[i].x, wb[0].z, acc[i].z);
            acc[i].w = fmaf(xa[i].x, wb[0].w, acc[i].w);
            acc[i].x = fmaf(xa[i].y, wb[1].x, acc[i].x);
            acc[i].y = fmaf(xa[i].y, wb[1].y, acc[i].y);
            acc[i].z = fmaf(xa[i].y, wb[1].z, acc[i].z);
            acc[i].w = fmaf(xa[i].y, wb[1].w, acc[i].w);
            acc[i].x = fmaf(xa[i].z, wb[2].x, acc[i].x);
            acc[i].y = fmaf(xa[i].z, wb[2].y, acc[i].y);
            acc[i].z = fmaf(xa[i].z, wb[2].z, acc[i].z);
            acc[i].w = fmaf(xa[i].z, wb[2].w, acc[i].w);
            acc[i].x = fmaf(xa[i].w, wb[3].x, acc[i].x);
            acc[i].y = fmaf(xa[i].w, wb[3].y, acc[i].y);
            acc[i].z = fmaf(xa[i].w, wb[3].z, acc[i].z);
            acc[i].w = fmaf(xa[i].w, wb[3].w, acc[i].w);
        }
    }

    // Store h rows as fp16 (8 B per node per thread). NOT nontemporal:
    // aggregate re-reads h immediately, we want it resident in L2/LLC.
    #pragma unroll
    for (int i = 0; i < 4; ++i) {
        int gn = node0 + n0 + i;
        if (gn < n_nodes) {
            half4_t hv;
            hv.x = (_Float16)acc[i].x;
            hv.y = (_Float16)acc[i].y;
            hv.z = (_Float16)acc[i].z;
            hv.w = (_Float16)acc[i].w;
            *(half4_t*)&h[(size_t)gn * D_OUT + d0] = hv;
        }
    }
}

// ---------------------------------------------------------------------------
// Kernel 2: out[i][:] = bias + sum_e vals[e] * h[src[e]][:]   (h is fp16)
// One wave per node; lane = (sub = lane>>4) edge slot x (d4 = lane&15)
// 8-byte half4 chunk. 16-edge main loop = 4 independent src->gather chains;
// f32 accumulate; nontemporal src/vals (streamed once) and out store.
// ---------------------------------------------------------------------------
__global__ __launch_bounds__(256) void aggregate_kernel(
    const half4_t* __restrict__ h4, const int* __restrict__ src,
    const float* __restrict__ vals, const int* __restrict__ row_ptr,
    const float* __restrict__ bias, float* __restrict__ out, int n_nodes)
{
    int wave = (blockIdx.x * blockDim.x + threadIdx.x) >> 6;
    int lane = threadIdx.x & 63;
    if (wave >= n_nodes) return;
    int sub = lane >> 4;      // edge slot 0..3
    int d4  = lane & 15;      // half4 chunk of the 64-dim row

    int b = row_ptr[wave];
    int e = row_ptr[wave + 1];

    // Hoisted: in flight during the whole gather loop.
    float4 bb = *(const float4*)&bias[d4 * 4];

    float4 acc0 = make_float4(0.f, 0.f, 0.f, 0.f);
    float4 acc1 = make_float4(0.f, 0.f, 0.f, 0.f);

    int k = b + sub;
    // 16 edges per iteration: 4 gathers in flight per wave.
    for (; k + 12 < e; k += 16) {
        int   s0 = __builtin_nontemporal_load(&src[k]);
        int   s1 = __builtin_nontemporal_load(&src[k + 4]);
        int   s2 = __builtin_nontemporal_load(&src[k + 8]);
        int   s3 = __builtin_nontemporal_load(&src[k + 12]);
        float v0 = __builtin_nontemporal_load(&vals[k]);
        float v1 = __builtin_nontemporal_load(&vals[k + 4]);
        float v2 = __builtin_nontemporal_load(&vals[k + 8]);
        float v3 = __builtin_nontemporal_load(&vals[k + 12]);
        half4_t h0 = h4[(size_t)s0 * 16 + d4];
        half4_t h1 = h4[(size_t)s1 * 16 + d4];
        half4_t h2 = h4[(size_t)s2 * 16 + d4];
        half4_t h3 = h4[(size_t)s3 * 16 + d4];
        acc0.x = fmaf(v0, (float)h0.x, acc0.x);
        acc0.y = fmaf(v0, (float)h0.y, acc0.y);
        acc0.z = fmaf(v0, (float)h0.z, acc0.z);
        acc0.w = fmaf(v0, (float)h0.w, acc0.w);
        acc1.x = fmaf(v1, (float)h1.x, acc1.x);
        acc1.y = fmaf(v1, (float)h1.y, acc1.y);
        acc1.z = fmaf(v1, (float)h1.z, acc1.z);
        acc1.w = fmaf(v1, (float)h1.w, acc1.w);
        acc0.x = fmaf(v2, (float)h2.x, acc0.x);
        acc0.y = fmaf(v2, (float)h2.y, acc0.y);
        acc0.z = fmaf(v2, (float)h2.z, acc0.z);
        acc0.w = fmaf(v2, (float)h2.w, acc0.w);
        acc1.x = fmaf(v3, (float)h3.x, acc1.x);
        acc1.y = fmaf(v3, (float)h3.y, acc1.y);
        acc1.z = fmaf(v3, (float)h3.z, acc1.z);
        acc1.w = fmaf(v3, (float)h3.w, acc1.w);
    }
    // 8-edge remainder.
    for (; k + 4 < e; k += 8) {
        int   s0 = __builtin_nontemporal_load(&src[k]);
        int   s1 = __builtin_nontemporal_load(&src[k + 4]);
        float v0 = __builtin_nontemporal_load(&vals[k]);
        float v1 = __builtin_nontemporal_load(&vals[k + 4]);
        half4_t h0 = h4[(size_t)s0 * 16 + d4];
        half4_t h1 = h4[(size_t)s1 * 16 + d4];
        acc0.x = fmaf(v0, (float)h0.x, acc0.x);
        acc0.y = fmaf(v0, (float)h0.y, acc0.y);
        acc0.z = fmaf(v0, (float)h0.z, acc0.z);
        acc0.w = fmaf(v0, (float)h0.w, acc0.w);
        acc1.x = fmaf(v1, (float)h1.x, acc1.x);
        acc1.y = fmaf(v1, (float)h1.y, acc1.y);
        acc1.z = fmaf(v1, (float)h1.z, acc1.z);
        acc1.w = fmaf(v1, (float)h1.w, acc1.w);
    }
    // 1-edge remainder.
    if (k < e) {
        int   s0 = src[k];
        float v0 = vals[k];
        half4_t h0 = h4[(size_t)s0 * 16 + d4];
        acc0.x = fmaf(v0, (float)h0.x, acc0.x);
        acc0.y = fmaf(v0, (float)h0.y, acc0.y);
        acc0.z = fmaf(v0, (float)h0.z, acc0.z);
        acc0.w = fmaf(v0, (float)h0.w, acc0.w);
    }

    float4 acc;
    acc.x = acc0.x + acc1.x;
    acc.y = acc0.y + acc1.y;
    acc.z = acc0.z + acc1.z;
    acc.w = acc0.w + acc1.w;

    // Sum across the 4 edge slots (lanes differing in bits 4,5).
    #pragma unroll
    for (int off = 16; off < 64; off <<= 1) {
        acc.x += __shfl_xor(acc.x, off, 64);
        acc.y += __shfl_xor(acc.y, off, 64);
        acc.z += __shfl_xor(acc.z, off, 64);
        acc.w += __shfl_xor(acc.w, off, 64);
    }

    if (sub == 0) {
        nfloat4 o;
        o.x = acc.x + bb.x;
        o.y = acc.y + bb.y;
        o.z = acc.z + bb.z;
        o.w = acc.w + bb.w;
        __builtin_nontemporal_store(o, (nfloat4*)&out[(size_t)wave * D_OUT + d4 * 4]);
    }
}

// ---------------------------------------------------------------------------
extern "C" void kernel_launch(void* const* d_in, const int* in_sizes, int n_in,
                              void* d_out, int out_size, void* d_ws, size_t ws_size,
                              hipStream_t stream)
{
    const float* x         = (const float*)d_in[0];
    const int*   edge_src  = (const int*)  d_in[1];
    const int*   edge_dst  = (const int*)  d_in[2];
    const float* edge_vals = (const float*)d_in[3];
    const float* weight    = (const float*)d_in[4];
    const float* bias      = (const float*)d_in[5];
    float*       out       = (float*)d_out;

    const int n_nodes = in_sizes[0] / D_IN;   // 50000
    const int n_edges = in_sizes[1];          // 800000

    // Workspace layout: h [n_nodes*64 fp16] | row_ptr [(n_nodes+1) i32]
    _Float16* h       = (_Float16*)d_ws;
    int*      row_ptr = (int*)((char*)d_ws + (size_t)n_nodes * D_OUT * sizeof(_Float16));

    // 1) fused: h = x @ W (fp16 out)  ||  row_ptr from sorted edge_dst
    {
        int gemm_blocks = (n_nodes + 63) / 64;            // 782
        int rp_blocks   = (n_edges + 1023) / 1024;        // 782
        dim3 grid(gemm_blocks + rp_blocks), block(256);
        hipLaunchKernelGGL(gemm_rowptr_kernel, grid, block, 0, stream,
                           x, weight, h, n_nodes,
                           edge_dst, row_ptr, n_edges, gemm_blocks);
    }
    // 2) aggregate + bias
    {
        dim3 grid((n_nodes + 3) / 4), block(256);   // 4 waves/block, 1 wave/node
        hipLaunchKernelGGL(aggregate_kernel, grid, block, 0, stream,
                           (const half4_t*)h, edge_src, edge_vals, row_ptr, bias, out, n_nodes);
    }
}